// Round 14
// baseline (179.714 us; speedup 1.0000x reference)
//
#include <hip/hip_runtime.h>

typedef float f32x4 __attribute__((ext_vector_type(4)));
typedef short s16x8 __attribute__((ext_vector_type(8)));
typedef unsigned short u16x4 __attribute__((ext_vector_type(4)));
typedef unsigned short u16x8 __attribute__((ext_vector_type(8)));
typedef unsigned short ushort_t;

__device__ __forceinline__ unsigned short f2bf(float f) {
    union { float f; unsigned int u; } v; v.f = f;
    unsigned int r = (v.u + 0x7fffu + ((v.u >> 16) & 1u)) >> 16;
    return (unsigned short)r;
}
__device__ __forceinline__ unsigned short tbf(float f) {  // truncate (f >= 0)
    union { float f; unsigned int u; } v; v.f = f;
    return (unsigned short)(v.u >> 16);
}
__device__ __forceinline__ float bf2f(unsigned short b) {
    union { unsigned int u; float f; } v; v.u = ((unsigned int)b) << 16;
    return v.f;
}

__device__ __forceinline__ f32x4 mfma_bf16(s16x8 a, s16x8 b, f32x4 c) {
    return __builtin_amdgcn_mfma_f32_16x16x32_bf16(a, b, c, 0, 0, 0);
}

__device__ __forceinline__ void gl_lds16(const void* g, void* l) {
    __builtin_amdgcn_global_load_lds(
        (const __attribute__((address_space(1))) unsigned int*)g,
        (__attribute__((address_space(3))) unsigned int*)l, 16, 0, 0);
}

// log2(e)/sqrt(512): fold exp->exp2 conversion into Q scale
#define QSCALE 0.06375871469f
// Fixed softmax offset (log2 domain) -- exact by shift-invariance; relu'd q,k
// keep scores in [0, ~16]; denominator >= 4096*2^-18 > 0.
#define FIXED_M 18.0f

// ---------------------------------------------------------------------------
// Kernel 0: cast x (8192x512) and Wq/Wk/Wv (512x512 each) fp32 -> bf16.
// One vec8 per thread. x -> xb, W -> wb (3 concatenated).
// total vec8 = 524288 (x) + 3*32768 (W) = 622592; grid = 2432 x 256.
// ---------------------------------------------------------------------------
__global__ __launch_bounds__(256) void cast_kernel(
    const float* __restrict__ x,
    const float* __restrict__ Wq, const float* __restrict__ Wk,
    const float* __restrict__ Wv,
    ushort_t* __restrict__ xb, ushort_t* __restrict__ wb)
{
    const int i = blockIdx.x * 256 + threadIdx.x;
    const float* src;
    ushort_t* dst;
    size_t off;
    if (i < 524288) {
        src = x; dst = xb; off = (size_t)i;
    } else {
        const int j = i - 524288;
        const int w = j >> 15;              // 0..2
        off = (size_t)(j & 32767);
        src = (w == 0) ? Wq : (w == 1) ? Wk : Wv;
        dst = wb + (size_t)w * 262144;
    }
    const float4 v0 = *reinterpret_cast<const float4*>(src + off * 8);
    const float4 v1 = *reinterpret_cast<const float4*>(src + off * 8 + 4);
    u16x8 p;
    p[0] = f2bf(v0.x); p[1] = f2bf(v0.y); p[2] = f2bf(v0.z); p[3] = f2bf(v0.w);
    p[4] = f2bf(v1.x); p[5] = f2bf(v1.y); p[6] = f2bf(v1.z); p[7] = f2bf(v1.w);
    *reinterpret_cast<u16x8*>(dst + off * 8) = p;
}

// ---------------------------------------------------------------------------
// Kernel 1b: lean bf16 projection GEMM. y = relu(xb @ W^T + b); q *= QSCALE.
// global_load_lds staging (no staging VALU), 32KB LDS dbuf -> 3 blocks/CU.
// 128x128 tile, BK=32, 4 waves 2x2, acc = 64 AGPR. grid = (64, 4, 3).
// q,k row-major; v transposed [batch][512][4096].
// ---------------------------------------------------------------------------
__global__ __launch_bounds__(256) void proj_bf16(
    const ushort_t* __restrict__ xb, const ushort_t* __restrict__ wb,
    const float* __restrict__ bq, const float* __restrict__ bk,
    const float* __restrict__ bv,
    ushort_t* __restrict__ qkv_ws)
{
    const int mblk  = blockIdx.x;
    const int nblk  = blockIdx.y;
    const int which = blockIdx.z;

    const ushort_t* W = wb + (size_t)which * 262144;
    const float* bias = (which == 0) ? bq : (which == 1) ? bk : bv;
    ushort_t* out = qkv_ws + (size_t)which * (8192u * 512u);
    const float scale = (which == 0) ? QSCALE : 1.0f;

    __shared__ ushort_t a_lds[2][128 * 32];   // 2 x 8KB
    __shared__ ushort_t b_lds[2][128 * 32];   // 2 x 8KB

    const int tid  = threadIdx.x;
    const int lane = tid & 63;
    const int wave = tid >> 6;
    const int wr = wave >> 1, wc = wave & 1;
    const int g = lane >> 4, l15 = lane & 15;

    f32x4 acc[4][4] = {};

    // chunk c (0..511): row = c>>2, part = c&3; dest byte = c*16 (linear)
#define PSTAGE(BUF, K0)                                                         \
    do {                                                                        \
        _Pragma("unroll")                                                       \
        for (int i = 0; i < 2; i++) {                                           \
            const int c = i * 256 + tid;                                        \
            gl_lds16(xb + (size_t)(mblk * 128 + (c >> 2)) * 512 + (K0) + (c & 3) * 8, \
                     (char*)&a_lds[BUF][0] + c * 16);                           \
        }                                                                       \
        _Pragma("unroll")                                                       \
        for (int i = 0; i < 2; i++) {                                           \
            const int c = i * 256 + tid;                                        \
            gl_lds16(W + (size_t)(nblk * 128 + (c >> 2)) * 512 + (K0) + (c & 3) * 8, \
                     (char*)&b_lds[BUF][0] + c * 16);                           \
        }                                                                       \
    } while (0)

    PSTAGE(0, 0);
    asm volatile("s_waitcnt vmcnt(0)" ::: "memory");
    __builtin_amdgcn_s_barrier();

    int cur = 0;
    for (int t = 0; t < 16; ++t) {
        if (t + 1 < 16) PSTAGE(cur ^ 1, (t + 1) * 32);

        s16x8 af[4], bf[4];
        #pragma unroll
        for (int m = 0; m < 4; m++)
            af[m] = *reinterpret_cast<const s16x8*>(
                (const char*)&a_lds[cur][0] + (wr * 64 + m * 16 + l15) * 64 + g * 16);
        #pragma unroll
        for (int n = 0; n < 4; n++)
            bf[n] = *reinterpret_cast<const s16x8*>(
                (const char*)&b_lds[cur][0] + (wc * 64 + n * 16 + l15) * 64 + g * 16);

        #pragma unroll
        for (int m = 0; m < 4; m++)
            #pragma unroll
            for (int n = 0; n < 4; n++)
                acc[m][n] = mfma_bf16(af[m], bf[n], acc[m][n]);

        asm volatile("s_waitcnt vmcnt(0) lgkmcnt(0)" ::: "memory");
        __builtin_amdgcn_sched_barrier(0);
        __builtin_amdgcn_s_barrier();
        cur ^= 1;
    }
#undef PSTAGE

    if (which == 2) {
        #pragma unroll
        for (int n = 0; n < 4; n++) {
            const int col = nblk * 128 + wc * 64 + n * 16 + l15;
            const float b = bias[col];
            #pragma unroll
            for (int m = 0; m < 4; m++) {
                const int rowb = mblk * 128 + wr * 64 + m * 16 + g * 4;
                const int batch = rowb >> 12, sr = rowb & 4095;
                u16x4 pk;
                #pragma unroll
                for (int j = 0; j < 4; j++)
                    pk[j] = f2bf(fmaxf(acc[m][n][j] + b, 0.0f));
                *reinterpret_cast<u16x4*>(out + (size_t)batch * 512 * 4096 +
                                          (size_t)col * 4096 + sr) = pk;
            }
        }
    } else {
        #pragma unroll
        for (int n = 0; n < 4; n++) {
            const int col = nblk * 128 + wc * 64 + n * 16 + l15;
            const float b = bias[col];
            #pragma unroll
            for (int m = 0; m < 4; m++) {
                #pragma unroll
                for (int j = 0; j < 4; j++) {
                    const int row = mblk * 128 + wr * 64 + m * 16 + g * 4 + j;
                    float v = fmaxf(acc[m][n][j] + b, 0.0f) * scale;
                    out[(size_t)row * 512 + col] = f2bf(v);
                }
            }
        }
    }
}

// ---------------------------------------------------------------------------
// Kernel 1-fallback: fused fp32-source projection (R13 version, used if ws
// lacks room for the cast scratch, i.e. SP < 2).
// ---------------------------------------------------------------------------
__global__ __launch_bounds__(256) void qkv_proj_fused(
    const float* __restrict__ x,
    const float* __restrict__ Wq, const float* __restrict__ bq,
    const float* __restrict__ Wk, const float* __restrict__ bk,
    const float* __restrict__ Wv, const float* __restrict__ bv,
    ushort_t* __restrict__ qkv_ws)
{
    const int mblk = blockIdx.x;
    const int nblk = blockIdx.y;

    __shared__ ushort_t a_lds[128][40];
    __shared__ ushort_t b_lds[3][128][40];

    const int tid  = threadIdx.x;
    const int lane = tid & 63;
    const int wave = tid >> 6;
    const int wr = wave >> 1, wc = wave & 1;

    f32x4 acc[3][4][4] = {};

    for (int k0 = 0; k0 < 512; k0 += 32) {
        #pragma unroll
        for (int i = 0; i < 4; i++) {
            const int chunk = i * 256 + tid;
            const int row = chunk >> 3, c4 = (chunk & 7) * 4;
            const float4 v = *reinterpret_cast<const float4*>(
                x + (size_t)(mblk * 128 + row) * 512 + k0 + c4);
            u16x4 pk;
            pk[0] = f2bf(v.x); pk[1] = f2bf(v.y);
            pk[2] = f2bf(v.z); pk[3] = f2bf(v.w);
            *reinterpret_cast<u16x4*>(&a_lds[row][c4]) = pk;
        }
        #pragma unroll
        for (int wsel = 0; wsel < 3; wsel++) {
            const float* W = (wsel == 0) ? Wq : (wsel == 1) ? Wk : Wv;
            #pragma unroll
            for (int i = 0; i < 4; i++) {
                const int chunk = i * 256 + tid;
                const int row = chunk >> 3, c4 = (chunk & 7) * 4;
                const float4 v = *reinterpret_cast<const float4*>(
                    W + (size_t)(nblk * 128 + row) * 512 + k0 + c4);
                u16x4 pk;
                pk[0] = f2bf(v.x); pk[1] = f2bf(v.y);
                pk[2] = f2bf(v.z); pk[3] = f2bf(v.w);
                *reinterpret_cast<u16x4*>(&b_lds[wsel][row][c4]) = pk;
            }
        }
        __syncthreads();

        s16x8 af[4];
        #pragma unroll
        for (int m = 0; m < 4; m++)
            af[m] = *reinterpret_cast<const s16x8*>(
                &a_lds[wr * 64 + m * 16 + (lane & 15)][(lane >> 4) * 8]);
        #pragma unroll
        for (int wsel = 0; wsel < 3; wsel++) {
            s16x8 bf[4];
            #pragma unroll
            for (int n = 0; n < 4; n++)
                bf[n] = *reinterpret_cast<const s16x8*>(
                    &b_lds[wsel][wc * 64 + n * 16 + (lane & 15)][(lane >> 4) * 8]);
            #pragma unroll
            for (int m = 0; m < 4; m++)
                #pragma unroll
                for (int n = 0; n < 4; n++)
                    acc[wsel][m][n] = mfma_bf16(af[m], bf[n], acc[wsel][m][n]);
        }
        __syncthreads();
    }

    #pragma unroll
    for (int wsel = 0; wsel < 3; wsel++) {
        const float* bias = (wsel == 0) ? bq : (wsel == 1) ? bk : bv;
        ushort_t* out = qkv_ws + (size_t)wsel * (8192u * 512u);
        const float scale = (wsel == 0) ? QSCALE : 1.0f;
        if (wsel == 2) {
            #pragma unroll
            for (int n = 0; n < 4; n++) {
                const int col = nblk * 128 + wc * 64 + n * 16 + (lane & 15);
                const float b = bias[col];
                #pragma unroll
                for (int m = 0; m < 4; m++) {
                    const int rowb = mblk * 128 + wr * 64 + m * 16 + (lane >> 4) * 4;
                    const int batch = rowb >> 12, sr = rowb & 4095;
                    u16x4 pk;
                    #pragma unroll
                    for (int j = 0; j < 4; j++)
                        pk[j] = f2bf(fmaxf(acc[2][m][n][j] + b, 0.0f));
                    *reinterpret_cast<u16x4*>(out + (size_t)batch * 512 * 4096 +
                                              (size_t)col * 4096 + sr) = pk;
                }
            }
        } else {
            #pragma unroll
            for (int n = 0; n < 4; n++) {
                const int col = nblk * 128 + wc * 64 + n * 16 + (lane & 15);
                const float b = bias[col];
                #pragma unroll
                for (int m = 0; m < 4; m++) {
                    #pragma unroll
                    for (int j = 0; j < 4; j++) {
                        const int row = mblk * 128 + wr * 64 + m * 16 + (lane >> 4) * 4 + j;
                        float v = fmaxf(acc[wsel][m][n][j] + b, 0.0f) * scale;
                        out[(size_t)row * 512 + col] = f2bf(v);
                    }
                }
            }
        }
    }
}

// ---------------------------------------------------------------------------
// Kernel 2: flash attention, D-SPLIT PV (v10) with slack-engineered staging:
// STAGE(t+1) issued AFTER bar1 (not tile-top). bar1 = vmcnt(0)+lgkm (only
// V(t), had full QK phase to land). bar2 = vmcnt(4)+lgkm (K(t+1) landed,
// V(t+1) rides through with all of QK(t+1) as slack). grid = (2*SP, 32).
// ---------------------------------------------------------------------------
__global__ __launch_bounds__(512, 2) void attn_v13(
    const ushort_t* __restrict__ qkv_ws,
    ushort_t* __restrict__ opart, float* __restrict__ ml,
    float* __restrict__ out, int SP, int NK)
{
    const int combo = blockIdx.x;
    const int batch = combo / SP;
    const int split = combo % SP;
    const int qblk  = blockIdx.y;
    const int tid = threadIdx.x, lane = tid & 63, wave = tid >> 6;
    const int kv00 = split * (4096 / SP);

    const ushort_t* q_ws  = qkv_ws;
    const ushort_t* k_ws  = qkv_ws + (size_t)8192 * 512;
    const ushort_t* vt_ws = qkv_ws + (size_t)2 * 8192 * 512;  // [batch][512][4096]
    const size_t base  = (size_t)batch * 4096 * 512;
    const size_t vbase = (size_t)batch * 512 * 4096;

    __shared__ ushort_t k_lds[2][32 * 512];    // 64KB, XOR-swizzled 1KB rows
    __shared__ ushort_t vt_lds[2][512 * 32];   // 64KB, XOR-swizzled 64B rows
    __shared__ ushort_t p_lds[128][36];        // 9KB shared P (pad 36)
    __shared__ float l_lds[128];

    const int g = lane >> 4;
    const int l15 = lane & 15;

    // resident Q: 16 rows/wave, 16 k-steps (64 VGPR)
    s16x8 qf[16];
    {
        const int qrow0 = qblk * 128 + wave * 16 + l15;
        const ushort_t* qp = q_ws + base + (size_t)qrow0 * 512 + g * 8;
        #pragma unroll
        for (int ks = 0; ks < 16; ks++)
            qf[ks] = *reinterpret_cast<const s16x8*>(qp + ks * 32);
    }

    const f32x4 zf = {0.f, 0.f, 0.f, 0.f};
    f32x4 o[8][4];   // O[128 rows][64-col slice]: 8 row-frags x 4 col-frags
    #pragma unroll
    for (int rf = 0; rf < 8; rf++)
        #pragma unroll
        for (int cf = 0; cf < 4; cf++) o[rf][cf] = zf;
    float lrow[4] = {0.f, 0.f, 0.f, 0.f};

    // K loads first (4), V loads second (4) -- FIFO order for counted vmcnt
#define STAGE(BUF, KV0)                                                         \
    do {                                                                        \
        _Pragma("unroll")                                                       \
        for (int i = 0; i < 4; i++) {                                           \
            const int C   = i * 8192 + tid * 16;                                \
            const int row = C >> 10;                                            \
            const int Lc  = (C & 1023) ^ ((row & 7) << 4);                      \
            gl_lds16(k_ws + base + (size_t)((KV0) + row) * 512 + (Lc >> 1),     \
                     (char*)&k_lds[BUF][0] + C);                                \
        }                                                                       \
        _Pragma("unroll")                                                       \
        for (int i = 0; i < 4; i++) {                                           \
            const int C    = i * 8192 + tid * 16;                               \
            const int drow = C >> 6;                                            \
            const int gc   = (C >> 4) & 3;                                      \
            const int gl   = gc ^ ((drow >> 1) & 3);                            \
            gl_lds16(vt_ws + vbase + (size_t)drow * 4096 + (KV0) + gl * 8,      \
                     (char*)&vt_lds[BUF][0] + C);                               \
        }                                                                       \
    } while (0)

    // prologue: K0 awaited; V0 rides into tile 0's QK
    STAGE(0, kv00);
    asm volatile("s_waitcnt vmcnt(4)" ::: "memory");
    __builtin_amdgcn_sched_barrier(0);
    __builtin_amdgcn_s_barrier();

    int cur = 0;
    for (int t = 0; t < NK; ++t) {
        // ---- QK^T : S[16 rows][32 keys] for this wave's rows
        const char* kb = (const char*)&k_lds[cur][0];
        f32x4 s0 = zf, s1 = zf;
        #pragma unroll
        for (int ks = 0; ks < 16; ++ks) {
            const int xr = (ks * 64 + g * 16) ^ ((l15 & 7) << 4);
            const s16x8 kf0 = *reinterpret_cast<const s16x8*>(kb + l15 * 1024 + xr);
            const s16x8 kf1 = *reinterpret_cast<const s16x8*>(kb + (16 + l15) * 1024 + xr);
            s0 = mfma_bf16(qf[ks], kf0, s0);
            s1 = mfma_bf16(qf[ks], kf1, s1);
        }

        // ---- P = exp2(S - FIXED_M) -> shared P LDS; per-lane l partials
        #pragma unroll
        for (int j = 0; j < 4; j++) {
            const float p0 = exp2f(s0[j] - FIXED_M);
            const float p1 = exp2f(s1[j] - FIXED_M);
            lrow[j] += p0 + p1;
            const int pr = wave * 16 + g * 4 + j;
            p_lds[pr][l15]      = tbf(p0);
            p_lds[pr][16 + l15] = tbf(p1);
        }

        // bar1: P visible + V(t) landed (only V(t) outstanding; QK covered it)
        asm volatile("s_waitcnt vmcnt(0) lgkmcnt(0)" ::: "memory");
        __builtin_amdgcn_sched_barrier(0);
        __builtin_amdgcn_s_barrier();
        __builtin_amdgcn_sched_barrier(0);

        // stage t+1 now: buffers cur^1 free (their readers retired by bar2(t-1))
        if (t + 1 < NK) STAGE(cur ^ 1, kv00 + (t + 1) * 32);

        // ---- PV (d-split): O[128 rows][wave's 64 cols] += P[128][32] @ V-slice
        {
            const char* vb = (const char*)&vt_lds[cur][0];
            s16x8 vf[4];
            #pragma unroll
            for (int cf = 0; cf < 4; cf++) {
                const int d = wave * 64 + cf * 16 + l15;
                vf[cf] = *reinterpret_cast<const s16x8*>(
                    vb + d * 64 + ((g * 16) ^ (((d >> 1) & 3) << 4)));
            }
            #pragma unroll
            for (int rf = 0; rf < 8; rf++) {
                const s16x8 pf = *reinterpret_cast<const s16x8*>(
                    &p_lds[rf * 16 + l15][g * 8]);
                #pragma unroll
                for (int cf = 0; cf < 4; cf++)
                    o[rf][cf] = mfma_bf16(pf, vf[cf], o[rf][cf]);
            }
        }

        // bar2: PV reads done (P reusable) + K(t+1) landed; V(t+1) in flight
        if (t + 1 < NK)
            asm volatile("s_waitcnt vmcnt(4) lgkmcnt(0)" ::: "memory");
        else
            asm volatile("s_waitcnt vmcnt(0) lgkmcnt(0)" ::: "memory");
        __builtin_amdgcn_sched_barrier(0);
        __builtin_amdgcn_s_barrier();
        __builtin_amdgcn_sched_barrier(0);
        cur ^= 1;
    }
#undef STAGE

    // ---- l: reduce across 16 key-lanes; publish per-row
    #pragma unroll
    for (int j = 0; j < 4; j++) {
        #pragma unroll
        for (int msk = 8; msk >= 1; msk >>= 1)
            lrow[j] += __shfl_xor(lrow[j], msk, 64);
    }
    if (l15 == 0) {
        #pragma unroll
        for (int j = 0; j < 4; j++)
            l_lds[wave * 16 + g * 4 + j] = lrow[j];
    }
    __builtin_amdgcn_s_barrier();

    const int qrowb = qblk * 128;
    if (opart != nullptr) {
        const size_t prow8k = (size_t)batch * 4096;
        if (l15 == 0) {
            #pragma unroll
            for (int j = 0; j < 4; j++) {
                const size_t r = prow8k + qrowb + wave * 16 + g * 4 + j;
                ml[((size_t)split * 8192 + r) * 2 + 1] = lrow[j];
            }
        }
        ushort_t* op = opart + (size_t)split * 8192 * 512;
        #pragma unroll
        for (int rf = 0; rf < 8; rf++) {
            #pragma unroll
            for (int cf = 0; cf < 4; cf++) {
                #pragma unroll
                for (int j = 0; j < 4; j++) {
                    const size_t r = prow8k + qrowb + rf * 16 + g * 4 + j;
                    op[r * 512 + wave * 64 + cf * 16 + l15] = f2bf(o[rf][cf][j]);
                }
            }
        }
    } else {
        #pragma unroll
        for (int rf = 0; rf < 8; rf++) {
            #pragma unroll
            for (int j = 0; j < 4; j++) {
                const int rl = rf * 16 + g * 4 + j;
                const float inv = 1.0f / l_lds[rl];
                #pragma unroll
                for (int cf = 0; cf < 4; cf++) {
                    out[base + (size_t)(qrowb + rl) * 512 + wave * 64 + cf * 16 + l15]
                        = o[rf][cf][j] * inv;
                }
            }
        }
    }
}

// ---------------------------------------------------------------------------
// Kernel 3: merge KV-split partials. Fixed-M => equal weights:
// out = (sum_s O_s) / (sum_s l_s). 1 wave/row, 4 rows/block.
// ---------------------------------------------------------------------------
__global__ __launch_bounds__(256) void merge_kernel(
    const ushort_t* __restrict__ opart, const float* __restrict__ ml,
    float* __restrict__ out, int SP)
{
    const int row  = blockIdx.x * 4 + (threadIdx.x >> 6);
    const int lane = threadIdx.x & 63;

    float denom = 0.0f;
    for (int s = 0; s < SP; s++)
        denom += ml[((size_t)s * 8192 + row) * 2 + 1];
    const float inv = 1.0f / denom;

    float acc[8] = {};
    for (int s = 0; s < SP; s++) {
        const s16x8 v = *reinterpret_cast<const s16x8*>(
            opart + ((size_t)s * 8192 + row) * 512 + lane * 8);
        #pragma unroll
        for (int i = 0; i < 8; i++)
            acc[i] += bf2f((ushort_t)v[i]);
    }
    float* dst = out + (size_t)row * 512 + lane * 8;
    #pragma unroll
    for (int i = 0; i < 8; i++) dst[i] = acc[i] * inv;
}

extern "C" void kernel_launch(void* const* d_in, const int* in_sizes, int n_in,
                              void* d_out, int out_size, void* d_ws, size_t ws_size,
                              hipStream_t stream) {
    const float* x  = (const float*)d_in[0];
    const float* Wq = (const float*)d_in[1];
    const float* bq = (const float*)d_in[2];
    const float* Wk = (const float*)d_in[3];
    const float* bk = (const float*)d_in[4];
    const float* Wv = (const float*)d_in[5];
    const float* bv = (const float*)d_in[6];
    float* out = (float*)d_out;
    ushort_t* qkv = (ushort_t*)d_ws;  // q | k | vt, each 8192*512 bf16
    (void)in_sizes; (void)n_in; (void)out_size;

    const size_t qkv_bytes = 3ull * 8192 * 512 * 2;  // 25165824

    int SP = 0;
    if (ws_size >= qkv_bytes + 4ull * (8388608 + 65536)) SP = 4;
    else if (ws_size >= qkv_bytes + 2ull * (8388608 + 65536)) SP = 2;
    else if (ws_size >= qkv_bytes + 1ull * (8388608 + 65536)) SP = 1;

    ushort_t* opart = qkv + 3ull * 8192 * 512;

    if (SP >= 2) {
        // scratch in dead opart space: xb (8.39MB) in slice 0, wb in slice 1
        ushort_t* xb = opart;
        ushort_t* wb = opart + (size_t)8192 * 512;
        cast_kernel<<<2432, 256, 0, stream>>>(x, Wq, Wk, Wv, xb, wb);
        dim3 gp(64, 4, 3);
        proj_bf16<<<gp, 256, 0, stream>>>(xb, wb, bq, bk, bv, qkv);
    } else {
        dim3 gp(64, 4);
        qkv_proj_fused<<<gp, 256, 0, stream>>>(x, Wq, bq, Wk, bk, Wv, bv, qkv);
    }

    if (SP > 0) {
        float* ml = (float*)(opart + (size_t)SP * 8192 * 512);
        dim3 ga(2 * SP, 32);
        attn_v13<<<ga, 512, 0, stream>>>(qkv, opart, ml, out, SP, (4096 / SP) / 32);
        merge_kernel<<<2048, 256, 0, stream>>>(opart, ml, out, SP);
    } else {
        dim3 ga(2, 32);
        attn_v13<<<ga, 512, 0, stream>>>(qkv, nullptr, nullptr, out, 1, 128);
    }
}

// Round 15
// 150.627 us; speedup vs baseline: 1.1931x; 1.1931x over previous
//
#include <hip/hip_runtime.h>

typedef float f32x4 __attribute__((ext_vector_type(4)));
typedef short s16x8 __attribute__((ext_vector_type(8)));
typedef unsigned short u16x4 __attribute__((ext_vector_type(4)));
typedef unsigned short ushort_t;

__device__ __forceinline__ unsigned short f2bf(float f) {
    union { float f; unsigned int u; } v; v.f = f;
    unsigned int r = (v.u + 0x7fffu + ((v.u >> 16) & 1u)) >> 16;
    return (unsigned short)r;
}
__device__ __forceinline__ unsigned short tbf(float f) {  // truncate (f >= 0)
    union { float f; unsigned int u; } v; v.f = f;
    return (unsigned short)(v.u >> 16);
}
__device__ __forceinline__ float bf2f(unsigned short b) {
    union { unsigned int u; float f; } v; v.u = ((unsigned int)b) << 16;
    return v.f;
}

__device__ __forceinline__ f32x4 mfma_bf16(s16x8 a, s16x8 b, f32x4 c) {
    return __builtin_amdgcn_mfma_f32_16x16x32_bf16(a, b, c, 0, 0, 0);
}

__device__ __forceinline__ void gl_lds16(const void* g, void* l) {
    __builtin_amdgcn_global_load_lds(
        (const __attribute__((address_space(1))) unsigned int*)g,
        (__attribute__((address_space(3))) unsigned int*)l, 16, 0, 0);
}

// log2(e)/sqrt(512): fold exp->exp2 conversion into Q scale
#define QSCALE 0.06375871469f
// Fixed softmax offset (log2 domain) -- exact by shift-invariance; relu'd q,k
// keep scores in [0, ~16]; denominator >= 4096*2^-18 > 0.
#define FIXED_M 18.0f

// ---------------------------------------------------------------------------
// Kernel 1: FUSED QKV projection. One block computes Q, K, V tiles for its
// (m,n): x staged+converted ONCE, float4 loads + packed u16x4 stores.
// q,k row-major [batch*4096][512] (q *= QSCALE); v TRANSPOSED
// [batch][512][4096]. grid = (64, 4), 256 thr, 4 waves 2x2.
// LDS rows padded to 40 ushorts (80B): 20-dword stride -> worst 2-way (free).
// ---------------------------------------------------------------------------
__global__ __launch_bounds__(256) void qkv_proj_fused(
    const float* __restrict__ x,
    const float* __restrict__ Wq, const float* __restrict__ bq,
    const float* __restrict__ Wk, const float* __restrict__ bk,
    const float* __restrict__ Wv, const float* __restrict__ bv,
    ushort_t* __restrict__ qkv_ws)
{
    const int mblk = blockIdx.x;
    const int nblk = blockIdx.y;

    __shared__ ushort_t a_lds[128][40];
    __shared__ ushort_t b_lds[3][128][40];

    const int tid  = threadIdx.x;
    const int lane = tid & 63;
    const int wave = tid >> 6;
    const int wr = wave >> 1, wc = wave & 1;

    f32x4 acc[3][4][4] = {};

    for (int k0 = 0; k0 < 512; k0 += 32) {
        // stage A (x) once: 128x32 fp32 -> bf16
        #pragma unroll
        for (int i = 0; i < 4; i++) {
            const int chunk = i * 256 + tid;           // 0..1023
            const int row = chunk >> 3, c4 = (chunk & 7) * 4;
            const float4 v = *reinterpret_cast<const float4*>(
                x + (size_t)(mblk * 128 + row) * 512 + k0 + c4);
            u16x4 pk;
            pk[0] = f2bf(v.x); pk[1] = f2bf(v.y);
            pk[2] = f2bf(v.z); pk[3] = f2bf(v.w);
            *reinterpret_cast<u16x4*>(&a_lds[row][c4]) = pk;
        }
        // stage B x3 (Wq, Wk, Wv)
        #pragma unroll
        for (int wsel = 0; wsel < 3; wsel++) {
            const float* W = (wsel == 0) ? Wq : (wsel == 1) ? Wk : Wv;
            #pragma unroll
            for (int i = 0; i < 4; i++) {
                const int chunk = i * 256 + tid;
                const int row = chunk >> 3, c4 = (chunk & 7) * 4;
                const float4 v = *reinterpret_cast<const float4*>(
                    W + (size_t)(nblk * 128 + row) * 512 + k0 + c4);
                u16x4 pk;
                pk[0] = f2bf(v.x); pk[1] = f2bf(v.y);
                pk[2] = f2bf(v.z); pk[3] = f2bf(v.w);
                *reinterpret_cast<u16x4*>(&b_lds[wsel][row][c4]) = pk;
            }
        }
        __syncthreads();

        s16x8 af[4];
        #pragma unroll
        for (int m = 0; m < 4; m++)
            af[m] = *reinterpret_cast<const s16x8*>(
                &a_lds[wr * 64 + m * 16 + (lane & 15)][(lane >> 4) * 8]);
        #pragma unroll
        for (int wsel = 0; wsel < 3; wsel++) {
            s16x8 bf[4];
            #pragma unroll
            for (int n = 0; n < 4; n++)
                bf[n] = *reinterpret_cast<const s16x8*>(
                    &b_lds[wsel][wc * 64 + n * 16 + (lane & 15)][(lane >> 4) * 8]);
            #pragma unroll
            for (int m = 0; m < 4; m++)
                #pragma unroll
                for (int n = 0; n < 4; n++)
                    acc[wsel][m][n] = mfma_bf16(af[m], bf[n], acc[wsel][m][n]);
        }
        __syncthreads();
    }

    // ---- epilogues: Q (scaled, row-major), K (row-major), V (transposed)
    #pragma unroll
    for (int wsel = 0; wsel < 3; wsel++) {
        const float* bias = (wsel == 0) ? bq : (wsel == 1) ? bk : bv;
        ushort_t* out = qkv_ws + (size_t)wsel * (8192u * 512u);
        const float scale = (wsel == 0) ? QSCALE : 1.0f;
        if (wsel == 2) {
            #pragma unroll
            for (int n = 0; n < 4; n++) {
                const int col = nblk * 128 + wc * 64 + n * 16 + (lane & 15);
                const float b = bias[col];
                #pragma unroll
                for (int m = 0; m < 4; m++) {
                    const int rowb = mblk * 128 + wr * 64 + m * 16 + (lane >> 4) * 4;
                    const int batch = rowb >> 12, sr = rowb & 4095;
                    u16x4 pk;
                    #pragma unroll
                    for (int j = 0; j < 4; j++)
                        pk[j] = f2bf(fmaxf(acc[2][m][n][j] + b, 0.0f));
                    *reinterpret_cast<u16x4*>(out + (size_t)batch * 512 * 4096 +
                                              (size_t)col * 4096 + sr) = pk;
                }
            }
        } else {
            #pragma unroll
            for (int n = 0; n < 4; n++) {
                const int col = nblk * 128 + wc * 64 + n * 16 + (lane & 15);
                const float b = bias[col];
                #pragma unroll
                for (int m = 0; m < 4; m++) {
                    #pragma unroll
                    for (int j = 0; j < 4; j++) {
                        const int row = mblk * 128 + wr * 64 + m * 16 + (lane >> 4) * 4 + j;
                        float v = fmaxf(acc[wsel][m][n][j] + b, 0.0f) * scale;
                        out[(size_t)row * 512 + col] = f2bf(v);
                    }
                }
            }
        }
    }
}

// ---------------------------------------------------------------------------
// Kernel 2: flash attention, D-SPLIT PV (v10 — proven 108.6us, restored
// verbatim). 8 waves x 512 thr, 128 q-rows/block. QK: wave owns 16 q-rows
// (qf=64 VGPR). PV: wave owns a 64-wide d-slice of O for ALL 128 rows
// (O=128 AGPR). 2 waves/SIMD. grid = (2*SP, 32).
// Schedule: STAGE(t+1) at tile-top; bar1 = lgkm(0) only; bar2 = vmcnt(0)+
// lgkm(0). Counted-vmcnt variants tested 3x (R12/R14) — all regress. Do not
// revisit.
// ---------------------------------------------------------------------------
__global__ __launch_bounds__(512, 2) void attn_v10(
    const ushort_t* __restrict__ qkv_ws,
    ushort_t* __restrict__ opart, float* __restrict__ ml,
    float* __restrict__ out, int SP, int NK)
{
    const int combo = blockIdx.x;
    const int batch = combo / SP;
    const int split = combo % SP;
    const int qblk  = blockIdx.y;
    const int tid = threadIdx.x, lane = tid & 63, wave = tid >> 6;
    const int kv00 = split * (4096 / SP);

    const ushort_t* q_ws  = qkv_ws;
    const ushort_t* k_ws  = qkv_ws + (size_t)8192 * 512;
    const ushort_t* vt_ws = qkv_ws + (size_t)2 * 8192 * 512;  // [batch][512][4096]
    const size_t base  = (size_t)batch * 4096 * 512;
    const size_t vbase = (size_t)batch * 512 * 4096;

    __shared__ ushort_t k_lds[2][32 * 512];    // 64KB, XOR-swizzled 1KB rows
    __shared__ ushort_t vt_lds[2][512 * 32];   // 64KB, XOR-swizzled 64B rows
    __shared__ ushort_t p_lds[128][36];        // 9KB shared P (pad 36)
    __shared__ float l_lds[128];

    const int g = lane >> 4;
    const int l15 = lane & 15;

    // resident Q: 16 rows/wave, 16 k-steps (64 VGPR)
    s16x8 qf[16];
    {
        const int qrow0 = qblk * 128 + wave * 16 + l15;
        const ushort_t* qp = q_ws + base + (size_t)qrow0 * 512 + g * 8;
        #pragma unroll
        for (int ks = 0; ks < 16; ks++)
            qf[ks] = *reinterpret_cast<const s16x8*>(qp + ks * 32);
    }

    const f32x4 zf = {0.f, 0.f, 0.f, 0.f};
    f32x4 o[8][4];   // O[128 rows][64-col slice]: 8 row-frags x 4 col-frags
    #pragma unroll
    for (int rf = 0; rf < 8; rf++)
        #pragma unroll
        for (int cf = 0; cf < 4; cf++) o[rf][cf] = zf;
    float lrow[4] = {0.f, 0.f, 0.f, 0.f};

#define STAGE(BUF, KV0)                                                         \
    do {                                                                        \
        _Pragma("unroll")                                                       \
        for (int i = 0; i < 4; i++) {                                           \
            const int C   = i * 8192 + tid * 16;                                \
            const int row = C >> 10;                                            \
            const int Lc  = (C & 1023) ^ ((row & 7) << 4);                      \
            gl_lds16(k_ws + base + (size_t)((KV0) + row) * 512 + (Lc >> 1),     \
                     (char*)&k_lds[BUF][0] + C);                                \
        }                                                                       \
        _Pragma("unroll")                                                       \
        for (int i = 0; i < 4; i++) {                                           \
            const int C    = i * 8192 + tid * 16;                               \
            const int drow = C >> 6;                                            \
            const int gc   = (C >> 4) & 3;                                      \
            const int gl   = gc ^ ((drow >> 1) & 3);                            \
            gl_lds16(vt_ws + vbase + (size_t)drow * 4096 + (KV0) + gl * 8,      \
                     (char*)&vt_lds[BUF][0] + C);                               \
        }                                                                       \
    } while (0)

    // prologue
    STAGE(0, kv00);
    asm volatile("s_waitcnt vmcnt(0)" ::: "memory");
    __builtin_amdgcn_s_barrier();

    int cur = 0;
    for (int t = 0; t < NK; ++t) {
        if (t + 1 < NK) STAGE(cur ^ 1, kv00 + (t + 1) * 32);

        // ---- QK^T : S[16 rows][32 keys] for this wave's rows
        const char* kb = (const char*)&k_lds[cur][0];
        f32x4 s0 = zf, s1 = zf;
        #pragma unroll
        for (int ks = 0; ks < 16; ++ks) {
            const int xr = (ks * 64 + g * 16) ^ ((l15 & 7) << 4);
            const s16x8 kf0 = *reinterpret_cast<const s16x8*>(kb + l15 * 1024 + xr);
            const s16x8 kf1 = *reinterpret_cast<const s16x8*>(kb + (16 + l15) * 1024 + xr);
            s0 = mfma_bf16(qf[ks], kf0, s0);
            s1 = mfma_bf16(qf[ks], kf1, s1);
        }

        // ---- P = exp2(S - FIXED_M) -> shared P LDS; per-lane l partials
        #pragma unroll
        for (int j = 0; j < 4; j++) {
            const float p0 = exp2f(s0[j] - FIXED_M);
            const float p1 = exp2f(s1[j] - FIXED_M);
            lrow[j] += p0 + p1;
            const int pr = wave * 16 + g * 4 + j;
            p_lds[pr][l15]      = tbf(p0);
            p_lds[pr][16 + l15] = tbf(p1);
        }

        // barrier(1): P complete + all QK reads of k-buf done
        asm volatile("s_waitcnt lgkmcnt(0)" ::: "memory");
        __builtin_amdgcn_sched_barrier(0);
        __builtin_amdgcn_s_barrier();
        __builtin_amdgcn_sched_barrier(0);

        // ---- PV (d-split): O[128 rows][wave's 64 cols] += P[128][32] @ V-slice
        {
            const char* vb = (const char*)&vt_lds[cur][0];
            s16x8 vf[4];
            #pragma unroll
            for (int cf = 0; cf < 4; cf++) {
                const int d = wave * 64 + cf * 16 + l15;
                vf[cf] = *reinterpret_cast<const s16x8*>(
                    vb + d * 64 + ((g * 16) ^ (((d >> 1) & 3) << 4)));
            }
            #pragma unroll
            for (int rf = 0; rf < 8; rf++) {
                const s16x8 pf = *reinterpret_cast<const s16x8*>(
                    &p_lds[rf * 16 + l15][g * 8]);
                #pragma unroll
                for (int cf = 0; cf < 4; cf++)
                    o[rf][cf] = mfma_bf16(pf, vf[cf], o[rf][cf]);
            }
        }

        // barrier(2): PV reads done (v-buf & P free); staged t+1 landed
        asm volatile("s_waitcnt vmcnt(0) lgkmcnt(0)" ::: "memory");
        __builtin_amdgcn_sched_barrier(0);
        __builtin_amdgcn_s_barrier();
        __builtin_amdgcn_sched_barrier(0);
        cur ^= 1;
    }
#undef STAGE

    // ---- l: reduce across 16 key-lanes; publish per-row
    #pragma unroll
    for (int j = 0; j < 4; j++) {
        #pragma unroll
        for (int msk = 8; msk >= 1; msk >>= 1)
            lrow[j] += __shfl_xor(lrow[j], msk, 64);
    }
    if (l15 == 0) {
        #pragma unroll
        for (int j = 0; j < 4; j++)
            l_lds[wave * 16 + g * 4 + j] = lrow[j];
    }
    __builtin_amdgcn_s_barrier();

    const int qrowb = qblk * 128;
    if (opart != nullptr) {
        const size_t prow8k = (size_t)batch * 4096;
        if (l15 == 0) {
            #pragma unroll
            for (int j = 0; j < 4; j++) {
                const size_t r = prow8k + qrowb + wave * 16 + g * 4 + j;
                ml[((size_t)split * 8192 + r) * 2 + 1] = lrow[j];
            }
        }
        ushort_t* op = opart + (size_t)split * 8192 * 512;
        #pragma unroll
        for (int rf = 0; rf < 8; rf++) {
            #pragma unroll
            for (int cf = 0; cf < 4; cf++) {
                #pragma unroll
                for (int j = 0; j < 4; j++) {
                    const size_t r = prow8k + qrowb + rf * 16 + g * 4 + j;
                    op[r * 512 + wave * 64 + cf * 16 + l15] = f2bf(o[rf][cf][j]);
                }
            }
        }
    } else {
        #pragma unroll
        for (int rf = 0; rf < 8; rf++) {
            #pragma unroll
            for (int j = 0; j < 4; j++) {
                const int rl = rf * 16 + g * 4 + j;
                const float inv = 1.0f / l_lds[rl];
                #pragma unroll
                for (int cf = 0; cf < 4; cf++) {
                    out[base + (size_t)(qrowb + rl) * 512 + wave * 64 + cf * 16 + l15]
                        = o[rf][cf][j] * inv;
                }
            }
        }
    }
}

// ---------------------------------------------------------------------------
// Kernel 3: merge KV-split partials. Fixed-M => equal weights:
// out = (sum_s O_s) / (sum_s l_s). 1 wave/row, 4 rows/block.
// ---------------------------------------------------------------------------
__global__ __launch_bounds__(256) void merge_kernel(
    const ushort_t* __restrict__ opart, const float* __restrict__ ml,
    float* __restrict__ out, int SP)
{
    const int row  = blockIdx.x * 4 + (threadIdx.x >> 6);
    const int lane = threadIdx.x & 63;

    float denom = 0.0f;
    for (int s = 0; s < SP; s++)
        denom += ml[((size_t)s * 8192 + row) * 2 + 1];
    const float inv = 1.0f / denom;

    float acc[8] = {};
    for (int s = 0; s < SP; s++) {
        const s16x8 v = *reinterpret_cast<const s16x8*>(
            opart + ((size_t)s * 8192 + row) * 512 + lane * 8);
        #pragma unroll
        for (int i = 0; i < 8; i++)
            acc[i] += bf2f((ushort_t)v[i]);
    }
    float* dst = out + (size_t)row * 512 + lane * 8;
    #pragma unroll
    for (int i = 0; i < 8; i++) dst[i] = acc[i] * inv;
}

extern "C" void kernel_launch(void* const* d_in, const int* in_sizes, int n_in,
                              void* d_out, int out_size, void* d_ws, size_t ws_size,
                              hipStream_t stream) {
    const float* x  = (const float*)d_in[0];
    const float* Wq = (const float*)d_in[1];
    const float* bq = (const float*)d_in[2];
    const float* Wk = (const float*)d_in[3];
    const float* bk = (const float*)d_in[4];
    const float* Wv = (const float*)d_in[5];
    const float* bv = (const float*)d_in[6];
    float* out = (float*)d_out;
    ushort_t* qkv = (ushort_t*)d_ws;  // q | k | vt, each 8192*512 bf16
    (void)in_sizes; (void)n_in; (void)out_size;

    const size_t qkv_bytes = 3ull * 8192 * 512 * 2;  // 25165824

    int SP = 0;
    if (ws_size >= qkv_bytes + 4ull * (8388608 + 65536)) SP = 4;
    else if (ws_size >= qkv_bytes + 2ull * (8388608 + 65536)) SP = 2;
    else if (ws_size >= qkv_bytes + 1ull * (8388608 + 65536)) SP = 1;

    dim3 gp(64, 4);
    qkv_proj_fused<<<gp, 256, 0, stream>>>(x, Wq, bq, Wk, bk, Wv, bv, qkv);

    if (SP > 0) {
        ushort_t* opart = qkv + 3ull * 8192 * 512;
        float* ml = (float*)(opart + (size_t)SP * 8192 * 512);
        dim3 ga(2 * SP, 32);
        attn_v10<<<ga, 512, 0, stream>>>(qkv, opart, ml, out, SP, (4096 / SP) / 32);
        merge_kernel<<<2048, 256, 0, stream>>>(opart, ml, out, SP);
    } else {
        dim3 ga(2, 32);
        attn_v10<<<ga, 512, 0, stream>>>(qkv, nullptr, nullptr, out, 1, 128);
    }
}

// Round 16
// 142.357 us; speedup vs baseline: 1.2624x; 1.0581x over previous
//
#include <hip/hip_runtime.h>

typedef float f32x4 __attribute__((ext_vector_type(4)));
typedef short s16x8 __attribute__((ext_vector_type(8)));
typedef unsigned short u16x4 __attribute__((ext_vector_type(4)));
typedef unsigned short u16x8 __attribute__((ext_vector_type(8)));
typedef unsigned short ushort_t;

__device__ __forceinline__ unsigned short f2bf(float f) {
    union { float f; unsigned int u; } v; v.f = f;
    unsigned int r = (v.u + 0x7fffu + ((v.u >> 16) & 1u)) >> 16;
    return (unsigned short)r;
}
__device__ __forceinline__ unsigned short tbf(float f) {  // truncate (f >= 0)
    union { float f; unsigned int u; } v; v.f = f;
    return (unsigned short)(v.u >> 16);
}
__device__ __forceinline__ float bf2f(unsigned short b) {
    union { unsigned int u; float f; } v; v.u = ((unsigned int)b) << 16;
    return v.f;
}

__device__ __forceinline__ f32x4 mfma_bf16(s16x8 a, s16x8 b, f32x4 c) {
    return __builtin_amdgcn_mfma_f32_16x16x32_bf16(a, b, c, 0, 0, 0);
}

__device__ __forceinline__ void gl_lds16(const void* g, void* l) {
    __builtin_amdgcn_global_load_lds(
        (const __attribute__((address_space(1))) unsigned int*)g,
        (__attribute__((address_space(3))) unsigned int*)l, 16, 0, 0);
}

// log2(e)/sqrt(512): fold exp->exp2 conversion into Q scale
#define QSCALE 0.06375871469f
// Fixed softmax offset (log2 domain) -- exact by shift-invariance; relu'd q,k
// keep scores in [0, ~16]; denominator >= 4096*2^-18 > 0.
#define FIXED_M 18.0f

// ---------------------------------------------------------------------------
// Kernel 0: cast x (8192x512) and Wq/Wk/Wv (512x512 each) fp32 -> bf16.
// One vec8 per thread. grid = 2432 x 256. (verified R14)
// ---------------------------------------------------------------------------
__global__ __launch_bounds__(256) void cast_kernel(
    const float* __restrict__ x,
    const float* __restrict__ Wq, const float* __restrict__ Wk,
    const float* __restrict__ Wv,
    ushort_t* __restrict__ xb, ushort_t* __restrict__ wb)
{
    const int i = blockIdx.x * 256 + threadIdx.x;
    const float* src;
    ushort_t* dst;
    size_t off;
    if (i < 524288) {
        src = x; dst = xb; off = (size_t)i;
    } else {
        const int j = i - 524288;
        const int w = j >> 15;              // 0..2
        off = (size_t)(j & 32767);
        src = (w == 0) ? Wq : (w == 1) ? Wk : Wv;
        dst = wb + (size_t)w * 262144;
    }
    const float4 v0 = *reinterpret_cast<const float4*>(src + off * 8);
    const float4 v1 = *reinterpret_cast<const float4*>(src + off * 8 + 4);
    u16x8 p;
    p[0] = f2bf(v0.x); p[1] = f2bf(v0.y); p[2] = f2bf(v0.z); p[3] = f2bf(v0.w);
    p[4] = f2bf(v1.x); p[5] = f2bf(v1.y); p[6] = f2bf(v1.z); p[7] = f2bf(v1.w);
    *reinterpret_cast<u16x8*>(dst + off * 8) = p;
}

// ---------------------------------------------------------------------------
// Kernel 1b: bf16 projection GEMM, swizzle-clean. y = relu(xb@W^T+b);
// q *= QSCALE. 128x128 tile, BK=64 (128B rows -> full (row&7)<<4 XOR swizzle;
// quarter-wave bank-starts = 8 distinct 16B slots x2 = b128 minimum).
// global_load_lds staging (zero staging VALU), 64KB LDS dbuf -> 2 blocks/CU.
// 4 waves 2x2, acc = 64 AGPR. grid = (64, 4, 3).
// ---------------------------------------------------------------------------
__global__ __launch_bounds__(256) void proj_bf16(
    const ushort_t* __restrict__ xb, const ushort_t* __restrict__ wb,
    const float* __restrict__ bq, const float* __restrict__ bk,
    const float* __restrict__ bv,
    ushort_t* __restrict__ qkv_ws)
{
    const int mblk  = blockIdx.x;
    const int nblk  = blockIdx.y;
    const int which = blockIdx.z;

    const ushort_t* W = wb + (size_t)which * 262144;
    const float* bias = (which == 0) ? bq : (which == 1) ? bk : bv;
    ushort_t* out = qkv_ws + (size_t)which * (8192u * 512u);
    const float scale = (which == 0) ? QSCALE : 1.0f;

    __shared__ ushort_t a_lds[2][128 * 64];   // 2 x 16KB
    __shared__ ushort_t b_lds[2][128 * 64];   // 2 x 16KB

    const int tid  = threadIdx.x;
    const int lane = tid & 63;
    const int wave = tid >> 6;
    const int wr = wave >> 1, wc = wave & 1;
    const int g = lane >> 4, l15 = lane & 15;

    f32x4 acc[4][4] = {};

    // stage 16KB/tile: 4 chunks/thread; linear LDS dest, inverse-XOR source.
#define PSTAGE(BUF, K0)                                                         \
    do {                                                                        \
        _Pragma("unroll")                                                       \
        for (int i = 0; i < 4; i++) {                                           \
            const int C    = i * 4096 + tid * 16;                               \
            const int row  = C >> 7;                                            \
            const int scol = (C & 127) ^ ((row & 7) << 4);                      \
            gl_lds16(xb + (size_t)(mblk * 128 + row) * 512 + (K0) + (scol >> 1),\
                     (char*)&a_lds[BUF][0] + C);                                \
        }                                                                       \
        _Pragma("unroll")                                                       \
        for (int i = 0; i < 4; i++) {                                           \
            const int C    = i * 4096 + tid * 16;                               \
            const int row  = C >> 7;                                            \
            const int scol = (C & 127) ^ ((row & 7) << 4);                      \
            gl_lds16(W + (size_t)(nblk * 128 + row) * 512 + (K0) + (scol >> 1), \
                     (char*)&b_lds[BUF][0] + C);                                \
        }                                                                       \
    } while (0)

    PSTAGE(0, 0);
    asm volatile("s_waitcnt vmcnt(0)" ::: "memory");
    __builtin_amdgcn_s_barrier();

    int cur = 0;
    for (int t = 0; t < 8; ++t) {
        if (t + 1 < 8) PSTAGE(cur ^ 1, (t + 1) * 64);

        // swizzled reads: row*128 + ((sl*64 + g*16) ^ ((row&7)<<4))
        s16x8 af[4][2], bf[4][2];
        #pragma unroll
        for (int m = 0; m < 4; m++) {
            const int row = wr * 64 + m * 16 + l15;
            #pragma unroll
            for (int sl = 0; sl < 2; sl++)
                af[m][sl] = *reinterpret_cast<const s16x8*>(
                    (const char*)&a_lds[cur][0] + row * 128 +
                    ((sl * 64 + g * 16) ^ ((row & 7) << 4)));
        }
        #pragma unroll
        for (int n = 0; n < 4; n++) {
            const int row = wc * 64 + n * 16 + l15;
            #pragma unroll
            for (int sl = 0; sl < 2; sl++)
                bf[n][sl] = *reinterpret_cast<const s16x8*>(
                    (const char*)&b_lds[cur][0] + row * 128 +
                    ((sl * 64 + g * 16) ^ ((row & 7) << 4)));
        }

        #pragma unroll
        for (int sl = 0; sl < 2; sl++)
            #pragma unroll
            for (int m = 0; m < 4; m++)
                #pragma unroll
                for (int n = 0; n < 4; n++)
                    acc[m][n] = mfma_bf16(af[m][sl], bf[n][sl], acc[m][n]);

        asm volatile("s_waitcnt vmcnt(0) lgkmcnt(0)" ::: "memory");
        __builtin_amdgcn_sched_barrier(0);
        __builtin_amdgcn_s_barrier();
        cur ^= 1;
    }
#undef PSTAGE

    if (which == 2) {
        // V: transposed store vt[batch][512][4096]
        #pragma unroll
        for (int n = 0; n < 4; n++) {
            const int col = nblk * 128 + wc * 64 + n * 16 + l15;
            const float b = bias[col];
            #pragma unroll
            for (int m = 0; m < 4; m++) {
                const int rowb = mblk * 128 + wr * 64 + m * 16 + g * 4;
                const int batch = rowb >> 12, sr = rowb & 4095;
                u16x4 pk;
                #pragma unroll
                for (int j = 0; j < 4; j++)
                    pk[j] = f2bf(fmaxf(acc[m][n][j] + b, 0.0f));
                *reinterpret_cast<u16x4*>(out + (size_t)batch * 512 * 4096 +
                                          (size_t)col * 4096 + sr) = pk;
            }
        }
    } else {
        #pragma unroll
        for (int n = 0; n < 4; n++) {
            const int col = nblk * 128 + wc * 64 + n * 16 + l15;
            const float b = bias[col];
            #pragma unroll
            for (int m = 0; m < 4; m++) {
                #pragma unroll
                for (int j = 0; j < 4; j++) {
                    const int row = mblk * 128 + wr * 64 + m * 16 + g * 4 + j;
                    float v = fmaxf(acc[m][n][j] + b, 0.0f) * scale;
                    out[(size_t)row * 512 + col] = f2bf(v);
                }
            }
        }
    }
}

// ---------------------------------------------------------------------------
// Kernel 1-fallback: fused fp32-source projection (used if SP < 2).
// ---------------------------------------------------------------------------
__global__ __launch_bounds__(256) void qkv_proj_fused(
    const float* __restrict__ x,
    const float* __restrict__ Wq, const float* __restrict__ bq,
    const float* __restrict__ Wk, const float* __restrict__ bk,
    const float* __restrict__ Wv, const float* __restrict__ bv,
    ushort_t* __restrict__ qkv_ws)
{
    const int mblk = blockIdx.x;
    const int nblk = blockIdx.y;

    __shared__ ushort_t a_lds[128][40];
    __shared__ ushort_t b_lds[3][128][40];

    const int tid  = threadIdx.x;
    const int lane = tid & 63;
    const int wave = tid >> 6;
    const int wr = wave >> 1, wc = wave & 1;

    f32x4 acc[3][4][4] = {};

    for (int k0 = 0; k0 < 512; k0 += 32) {
        #pragma unroll
        for (int i = 0; i < 4; i++) {
            const int chunk = i * 256 + tid;
            const int row = chunk >> 3, c4 = (chunk & 7) * 4;
            const float4 v = *reinterpret_cast<const float4*>(
                x + (size_t)(mblk * 128 + row) * 512 + k0 + c4);
            u16x4 pk;
            pk[0] = f2bf(v.x); pk[1] = f2bf(v.y);
            pk[2] = f2bf(v.z); pk[3] = f2bf(v.w);
            *reinterpret_cast<u16x4*>(&a_lds[row][c4]) = pk;
        }
        #pragma unroll
        for (int wsel = 0; wsel < 3; wsel++) {
            const float* W = (wsel == 0) ? Wq : (wsel == 1) ? Wk : Wv;
            #pragma unroll
            for (int i = 0; i < 4; i++) {
                const int chunk = i * 256 + tid;
                const int row = chunk >> 3, c4 = (chunk & 7) * 4;
                const float4 v = *reinterpret_cast<const float4*>(
                    W + (size_t)(nblk * 128 + row) * 512 + k0 + c4);
                u16x4 pk;
                pk[0] = f2bf(v.x); pk[1] = f2bf(v.y);
                pk[2] = f2bf(v.z); pk[3] = f2bf(v.w);
                *reinterpret_cast<u16x4*>(&b_lds[wsel][row][c4]) = pk;
            }
        }
        __syncthreads();

        s16x8 af[4];
        #pragma unroll
        for (int m = 0; m < 4; m++)
            af[m] = *reinterpret_cast<const s16x8*>(
                &a_lds[wr * 64 + m * 16 + (lane & 15)][(lane >> 4) * 8]);
        #pragma unroll
        for (int wsel = 0; wsel < 3; wsel++) {
            s16x8 bf[4];
            #pragma unroll
            for (int n = 0; n < 4; n++)
                bf[n] = *reinterpret_cast<const s16x8*>(
                    &b_lds[wsel][wc * 64 + n * 16 + (lane & 15)][(lane >> 4) * 8]);
            #pragma unroll
            for (int m = 0; m < 4; m++)
                #pragma unroll
                for (int n = 0; n < 4; n++)
                    acc[wsel][m][n] = mfma_bf16(af[m], bf[n], acc[wsel][m][n]);
        }
        __syncthreads();
    }

    #pragma unroll
    for (int wsel = 0; wsel < 3; wsel++) {
        const float* bias = (wsel == 0) ? bq : (wsel == 1) ? bk : bv;
        ushort_t* out = qkv_ws + (size_t)wsel * (8192u * 512u);
        const float scale = (wsel == 0) ? QSCALE : 1.0f;
        if (wsel == 2) {
            #pragma unroll
            for (int n = 0; n < 4; n++) {
                const int col = nblk * 128 + wc * 64 + n * 16 + (lane & 15);
                const float b = bias[col];
                #pragma unroll
                for (int m = 0; m < 4; m++) {
                    const int rowb = mblk * 128 + wr * 64 + m * 16 + (lane >> 4) * 4;
                    const int batch = rowb >> 12, sr = rowb & 4095;
                    u16x4 pk;
                    #pragma unroll
                    for (int j = 0; j < 4; j++)
                        pk[j] = f2bf(fmaxf(acc[2][m][n][j] + b, 0.0f));
                    *reinterpret_cast<u16x4*>(out + (size_t)batch * 512 * 4096 +
                                              (size_t)col * 4096 + sr) = pk;
                }
            }
        } else {
            #pragma unroll
            for (int n = 0; n < 4; n++) {
                const int col = nblk * 128 + wc * 64 + n * 16 + (lane & 15);
                const float b = bias[col];
                #pragma unroll
                for (int m = 0; m < 4; m++) {
                    #pragma unroll
                    for (int j = 0; j < 4; j++) {
                        const int row = mblk * 128 + wr * 64 + m * 16 + (lane >> 4) * 4 + j;
                        float v = fmaxf(acc[wsel][m][n][j] + b, 0.0f) * scale;
                        out[(size_t)row * 512 + col] = f2bf(v);
                    }
                }
            }
        }
    }
}

// ---------------------------------------------------------------------------
// Kernel 2: flash attention, D-SPLIT PV (v10 — proven 108.6us, frozen).
// 8 waves x 512 thr, 128 q-rows/block. QK: wave owns 16 q-rows (qf=64 VGPR).
// PV: wave owns a 64-wide d-slice of O for ALL 128 rows (O=128 AGPR).
// 2 waves/SIMD. grid = (2*SP, 32). Counted-vmcnt variants tested 3x — all
// regress; do not revisit.
// ---------------------------------------------------------------------------
__global__ __launch_bounds__(512, 2) void attn_v10(
    const ushort_t* __restrict__ qkv_ws,
    ushort_t* __restrict__ opart, float* __restrict__ ml,
    float* __restrict__ out, int SP, int NK)
{
    const int combo = blockIdx.x;
    const int batch = combo / SP;
    const int split = combo % SP;
    const int qblk  = blockIdx.y;
    const int tid = threadIdx.x, lane = tid & 63, wave = tid >> 6;
    const int kv00 = split * (4096 / SP);

    const ushort_t* q_ws  = qkv_ws;
    const ushort_t* k_ws  = qkv_ws + (size_t)8192 * 512;
    const ushort_t* vt_ws = qkv_ws + (size_t)2 * 8192 * 512;  // [batch][512][4096]
    const size_t base  = (size_t)batch * 4096 * 512;
    const size_t vbase = (size_t)batch * 512 * 4096;

    __shared__ ushort_t k_lds[2][32 * 512];    // 64KB, XOR-swizzled 1KB rows
    __shared__ ushort_t vt_lds[2][512 * 32];   // 64KB, XOR-swizzled 64B rows
    __shared__ ushort_t p_lds[128][36];        // 9KB shared P (pad 36)
    __shared__ float l_lds[128];

    const int g = lane >> 4;
    const int l15 = lane & 15;

    // resident Q: 16 rows/wave, 16 k-steps (64 VGPR)
    s16x8 qf[16];
    {
        const int qrow0 = qblk * 128 + wave * 16 + l15;
        const ushort_t* qp = q_ws + base + (size_t)qrow0 * 512 + g * 8;
        #pragma unroll
        for (int ks = 0; ks < 16; ks++)
            qf[ks] = *reinterpret_cast<const s16x8*>(qp + ks * 32);
    }

    const f32x4 zf = {0.f, 0.f, 0.f, 0.f};
    f32x4 o[8][4];   // O[128 rows][64-col slice]: 8 row-frags x 4 col-frags
    #pragma unroll
    for (int rf = 0; rf < 8; rf++)
        #pragma unroll
        for (int cf = 0; cf < 4; cf++) o[rf][cf] = zf;
    float lrow[4] = {0.f, 0.f, 0.f, 0.f};

#define STAGE(BUF, KV0)                                                         \
    do {                                                                        \
        _Pragma("unroll")                                                       \
        for (int i = 0; i < 4; i++) {                                           \
            const int C   = i * 8192 + tid * 16;                                \
            const int row = C >> 10;                                            \
            const int Lc  = (C & 1023) ^ ((row & 7) << 4);                      \
            gl_lds16(k_ws + base + (size_t)((KV0) + row) * 512 + (Lc >> 1),     \
                     (char*)&k_lds[BUF][0] + C);                                \
        }                                                                       \
        _Pragma("unroll")                                                       \
        for (int i = 0; i < 4; i++) {                                           \
            const int C    = i * 8192 + tid * 16;                               \
            const int drow = C >> 6;                                            \
            const int gc   = (C >> 4) & 3;                                      \
            const int gl   = gc ^ ((drow >> 1) & 3);                            \
            gl_lds16(vt_ws + vbase + (size_t)drow * 4096 + (KV0) + gl * 8,      \
                     (char*)&vt_lds[BUF][0] + C);                               \
        }                                                                       \
    } while (0)

    // prologue
    STAGE(0, kv00);
    asm volatile("s_waitcnt vmcnt(0)" ::: "memory");
    __builtin_amdgcn_s_barrier();

    int cur = 0;
    for (int t = 0; t < NK; ++t) {
        if (t + 1 < NK) STAGE(cur ^ 1, kv00 + (t + 1) * 32);

        // ---- QK^T : S[16 rows][32 keys] for this wave's rows
        const char* kb = (const char*)&k_lds[cur][0];
        f32x4 s0 = zf, s1 = zf;
        #pragma unroll
        for (int ks = 0; ks < 16; ++ks) {
            const int xr = (ks * 64 + g * 16) ^ ((l15 & 7) << 4);
            const s16x8 kf0 = *reinterpret_cast<const s16x8*>(kb + l15 * 1024 + xr);
            const s16x8 kf1 = *reinterpret_cast<const s16x8*>(kb + (16 + l15) * 1024 + xr);
            s0 = mfma_bf16(qf[ks], kf0, s0);
            s1 = mfma_bf16(qf[ks], kf1, s1);
        }

        // ---- P = exp2(S - FIXED_M) -> shared P LDS; per-lane l partials
        #pragma unroll
        for (int j = 0; j < 4; j++) {
            const float p0 = exp2f(s0[j] - FIXED_M);
            const float p1 = exp2f(s1[j] - FIXED_M);
            lrow[j] += p0 + p1;
            const int pr = wave * 16 + g * 4 + j;
            p_lds[pr][l15]      = tbf(p0);
            p_lds[pr][16 + l15] = tbf(p1);
        }

        // barrier(1): P complete + all QK reads of k-buf done
        asm volatile("s_waitcnt lgkmcnt(0)" ::: "memory");
        __builtin_amdgcn_sched_barrier(0);
        __builtin_amdgcn_s_barrier();
        __builtin_amdgcn_sched_barrier(0);

        // ---- PV (d-split): O[128 rows][wave's 64 cols] += P[128][32] @ V-slice
        {
            const char* vb = (const char*)&vt_lds[cur][0];
            s16x8 vf[4];
            #pragma unroll
            for (int cf = 0; cf < 4; cf++) {
                const int d = wave * 64 + cf * 16 + l15;
                vf[cf] = *reinterpret_cast<const s16x8*>(
                    vb + d * 64 + ((g * 16) ^ (((d >> 1) & 3) << 4)));
            }
            #pragma unroll
            for (int rf = 0; rf < 8; rf++) {
                const s16x8 pf = *reinterpret_cast<const s16x8*>(
                    &p_lds[rf * 16 + l15][g * 8]);
                #pragma unroll
                for (int cf = 0; cf < 4; cf++)
                    o[rf][cf] = mfma_bf16(pf, vf[cf], o[rf][cf]);
            }
        }

        // barrier(2): PV reads done (v-buf & P free); staged t+1 landed
        asm volatile("s_waitcnt vmcnt(0) lgkmcnt(0)" ::: "memory");
        __builtin_amdgcn_sched_barrier(0);
        __builtin_amdgcn_s_barrier();
        __builtin_amdgcn_sched_barrier(0);
        cur ^= 1;
    }
#undef STAGE

    // ---- l: reduce across 16 key-lanes; publish per-row
    #pragma unroll
    for (int j = 0; j < 4; j++) {
        #pragma unroll
        for (int msk = 8; msk >= 1; msk >>= 1)
            lrow[j] += __shfl_xor(lrow[j], msk, 64);
    }
    if (l15 == 0) {
        #pragma unroll
        for (int j = 0; j < 4; j++)
            l_lds[wave * 16 + g * 4 + j] = lrow[j];
    }
    __builtin_amdgcn_s_barrier();

    const int qrowb = qblk * 128;
    if (opart != nullptr) {
        const size_t prow8k = (size_t)batch * 4096;
        if (l15 == 0) {
            #pragma unroll
            for (int j = 0; j < 4; j++) {
                const size_t r = prow8k + qrowb + wave * 16 + g * 4 + j;
                ml[((size_t)split * 8192 + r) * 2 + 1] = lrow[j];
            }
        }
        ushort_t* op = opart + (size_t)split * 8192 * 512;
        #pragma unroll
        for (int rf = 0; rf < 8; rf++) {
            #pragma unroll
            for (int cf = 0; cf < 4; cf++) {
                #pragma unroll
                for (int j = 0; j < 4; j++) {
                    const size_t r = prow8k + qrowb + rf * 16 + g * 4 + j;
                    op[r * 512 + wave * 64 + cf * 16 + l15] = f2bf(o[rf][cf][j]);
                }
            }
        }
    } else {
        #pragma unroll
        for (int rf = 0; rf < 8; rf++) {
            #pragma unroll
            for (int j = 0; j < 4; j++) {
                const int rl = rf * 16 + g * 4 + j;
                const float inv = 1.0f / l_lds[rl];
                #pragma unroll
                for (int cf = 0; cf < 4; cf++) {
                    out[base + (size_t)(qrowb + rl) * 512 + wave * 64 + cf * 16 + l15]
                        = o[rf][cf][j] * inv;
                }
            }
        }
    }
}

// ---------------------------------------------------------------------------
// Kernel 3: merge KV-split partials. Fixed-M => equal weights:
// out = (sum_s O_s) / (sum_s l_s). 1 wave/row, 4 rows/block.
// ---------------------------------------------------------------------------
__global__ __launch_bounds__(256) void merge_kernel(
    const ushort_t* __restrict__ opart, const float* __restrict__ ml,
    float* __restrict__ out, int SP)
{
    const int row  = blockIdx.x * 4 + (threadIdx.x >> 6);
    const int lane = threadIdx.x & 63;

    float denom = 0.0f;
    for (int s = 0; s < SP; s++)
        denom += ml[((size_t)s * 8192 + row) * 2 + 1];
    const float inv = 1.0f / denom;

    float acc[8] = {};
    for (int s = 0; s < SP; s++) {
        const s16x8 v = *reinterpret_cast<const s16x8*>(
            opart + ((size_t)s * 8192 + row) * 512 + lane * 8);
        #pragma unroll
        for (int i = 0; i < 8; i++)
            acc[i] += bf2f((ushort_t)v[i]);
    }
    float* dst = out + (size_t)row * 512 + lane * 8;
    #pragma unroll
    for (int i = 0; i < 8; i++) dst[i] = acc[i] * inv;
}

extern "C" void kernel_launch(void* const* d_in, const int* in_sizes, int n_in,
                              void* d_out, int out_size, void* d_ws, size_t ws_size,
                              hipStream_t stream) {
    const float* x  = (const float*)d_in[0];
    const float* Wq = (const float*)d_in[1];
    const float* bq = (const float*)d_in[2];
    const float* Wk = (const float*)d_in[3];
    const float* bk = (const float*)d_in[4];
    const float* Wv = (const float*)d_in[5];
    const float* bv = (const float*)d_in[6];
    float* out = (float*)d_out;
    ushort_t* qkv = (ushort_t*)d_ws;  // q | k | vt, each 8192*512 bf16
    (void)in_sizes; (void)n_in; (void)out_size;

    const size_t qkv_bytes = 3ull * 8192 * 512 * 2;  // 25165824

    int SP = 0;
    if (ws_size >= qkv_bytes + 4ull * (8388608 + 65536)) SP = 4;
    else if (ws_size >= qkv_bytes + 2ull * (8388608 + 65536)) SP = 2;
    else if (ws_size >= qkv_bytes + 1ull * (8388608 + 65536)) SP = 1;

    ushort_t* opart = qkv + 3ull * 8192 * 512;

    if (SP >= 2) {
        // scratch in dead opart space: xb (8.39MB) slice 0, wb (1.6MB) slice 1
        ushort_t* xb = opart;
        ushort_t* wb = opart + (size_t)8192 * 512;
        cast_kernel<<<2432, 256, 0, stream>>>(x, Wq, Wk, Wv, xb, wb);
        dim3 gp(64, 4, 3);
        proj_bf16<<<gp, 256, 0, stream>>>(xb, wb, bq, bk, bv, qkv);
    } else {
        dim3 gp(64, 4);
        qkv_proj_fused<<<gp, 256, 0, stream>>>(x, Wq, bq, Wk, bk, Wv, bv, qkv);
    }

    if (SP > 0) {
        float* ml = (float*)(opart + (size_t)SP * 8192 * 512);
        dim3 ga(2 * SP, 32);
        attn_v10<<<ga, 512, 0, stream>>>(qkv, opart, ml, out, SP, (4096 / SP) / 32);
        merge_kernel<<<2048, 256, 0, stream>>>(opart, ml, out, SP);
    } else {
        dim3 ga(2, 32);
        attn_v10<<<ga, 512, 0, stream>>>(qkv, nullptr, nullptr, out, 1, 128);
    }
}